// Round 5
// baseline (828.204 us; speedup 1.0000x reference)
//
#include <hip/hip_runtime.h>

#define LEAF   16384
#define NNODE  (2*LEAF-1)
#define LATENT 256
#define HIDDEN 512
#define SYM    64
#define BOX    128

using half8 = __attribute__((ext_vector_type(8))) _Float16;
using f32x4 = __attribute__((ext_vector_type(4))) float;

__device__ __forceinline__ f32x4 mfma16h(half8 a, half8 b, f32x4 c){
    return __builtin_amdgcn_mfma_f32_16x16x32_f16(a, b, c, 0, 0, 0);
}

// ---------------------------------------------------------------------------
// Weight pack (fp16, MFMA B-fragment order):
// pk[cb][ks][tile][lane][j]; k = ks*32+(lane>>4)*8+j; col = cb*64+tile*16+(lane&15)
// ---------------------------------------------------------------------------
__global__ void pack_kernel(const float* __restrict__ A, const float* __restrict__ B,
                            int Ksplit, int N, int KS, _Float16* __restrict__ pk, int total)
{
    int t = blockIdx.x*256 + threadIdx.x;
    if (t >= total) return;
    int j = t & 7, l = (t>>3)&63, tile = (t>>9)&3;
    int rest = t >> 11;
    int ks = rest % KS, cb = rest / KS;
    int k   = ks*32 + ((l>>4)*8) + j;
    int col = cb*64 + tile*16 + (l&15);
    float wv = (k < Ksplit) ? A[(size_t)k*N + col] : B[(size_t)(k-Ksplit)*N + col];
    pk[((size_t)(cb*KS + ks)*4 + tile)*512 + (size_t)l*8 + j] = (_Float16)wv;
}

// ---------------------------------------------------------------------------
// Leaf: h[r][c] = tanh(sum_k shape[k][r]*Wb[k][c] + bb[c]) -> fp16
// ---------------------------------------------------------------------------
__global__ __launch_bounds__(256) void leaf_kernel(
    const float* __restrict__ shape, const float* __restrict__ Wb,
    const float* __restrict__ bb, _Float16* __restrict__ hh)
{
    __shared__ float Xs[16][132];
    const int r0 = blockIdx.x * 16;
    const int t  = threadIdx.x;
    for (int it = 0; it < 2; ++it) {
        int task = t + it * 256;
        int r  = task & 15;
        int kg = task >> 4;
        #pragma unroll
        for (int j = 0; j < 4; ++j)
            Xs[r][4*kg + j] = shape[(size_t)(4*kg + j) * LEAF + r0 + r];
    }
    __syncthreads();
    float acc[16];
    #pragma unroll
    for (int r = 0; r < 16; ++r) acc[r] = 0.f;
    const int c = t;
    for (int k = 0; k < BOX; k += 4) {
        float w0 = Wb[(k+0)*LATENT + c];
        float w1 = Wb[(k+1)*LATENT + c];
        float w2 = Wb[(k+2)*LATENT + c];
        float w3 = Wb[(k+3)*LATENT + c];
        #pragma unroll
        for (int r = 0; r < 16; ++r) {
            float4 x = *reinterpret_cast<const float4*>(&Xs[r][k]);
            acc[r] = fmaf(x.x, w0, acc[r]);
            acc[r] = fmaf(x.y, w1, acc[r]);
            acc[r] = fmaf(x.z, w2, acc[r]);
            acc[r] = fmaf(x.w, w3, acc[r]);
        }
    }
    float bias = bb[c];
    #pragma unroll
    for (int r = 0; r < 16; ++r)
        hh[(size_t)(r0 + r) * LATENT + c] = (_Float16)tanhf(acc[r] + bias);
}

// ---------------------------------------------------------------------------
// k1 body: stage-1. cb<8: U cols (K=512 from [a|b]); cb>=8: V cols (K=320: a+param)
// Block: 4 waves, NSUB*64 rows x 64 cols. B double-buffered in LDS (4KB/buf).
// ---------------------------------------------------------------------------
template<int NSUB>
__device__ __forceinline__ void k1_body(
    int rb, int cb, int start, int n,
    const _Float16* __restrict__ hh, const float* __restrict__ param,
    const _Float16* __restrict__ wcatpk, const _Float16* __restrict__ wscatpk,
    const float* __restrict__ b1, const float* __restrict__ bs1,
    _Float16* __restrict__ U, _Float16* __restrict__ V)
{
    __shared__ __align__(16) _Float16 ldsB1[2*2048];
    const int t = threadIdx.x, lane = t & 63, w = t >> 6;
    const bool isV = cb >= 8;
    const int cbl = isV ? cb - 8 : cb;
    const int KS  = isV ? 10 : 16;
    const _Float16* pk = (isV ? wscatpk : wcatpk) + (size_t)cbl * KS * 2048;
    const int row0  = rb * NSUB * 64;
    const int cbase = 2 * (start - LEAF);

    f32x4 acc[NSUB][4];
    #pragma unroll
    for (int s = 0; s < NSUB; ++s)
        #pragma unroll
        for (int c = 0; c < 4; ++c) acc[s][c] = (f32x4){0.f,0.f,0.f,0.f};

    *(half8*)(ldsB1 + t*8) = *(const half8*)(pk + (size_t)t*8);
    __syncthreads();

    for (int ks = 0; ks < KS; ++ks) {
        const bool hasNext = ks + 1 < KS;
        half8 stg;
        if (hasNext) stg = *(const half8*)(pk + (size_t)(ks+1)*2048 + (size_t)t*8);
        half8 A[NSUB];
        #pragma unroll
        for (int s = 0; s < NSUB; ++s) {
            int m = row0 + (s*4 + w)*16 + (lane & 15);
            if (m >= n) m = n - 1;
            if (!isV || ks < 8) {
                int node = cbase + 2*m + (ks >= 8 ? 1 : 0);
                A[s] = *(const half8*)(hh + (size_t)node*256 + (size_t)(ks & 7)*32 + ((lane >> 4)*8));
            } else {
                const float* pp = param + (size_t)(cbase + 2*m)*64 + (ks - 8)*32 + (lane >> 4)*8;
                float4 p0 = *(const float4*)pp;
                float4 p1 = *(const float4*)(pp + 4);
                A[s][0]=(_Float16)p0.x; A[s][1]=(_Float16)p0.y; A[s][2]=(_Float16)p0.z; A[s][3]=(_Float16)p0.w;
                A[s][4]=(_Float16)p1.x; A[s][5]=(_Float16)p1.y; A[s][6]=(_Float16)p1.z; A[s][7]=(_Float16)p1.w;
            }
        }
        const _Float16* lb = ldsB1 + (ks & 1)*2048;
        #pragma unroll
        for (int tile = 0; tile < 4; ++tile) {
            half8 Bh = *(const half8*)(lb + tile*512 + lane*8);
            #pragma unroll
            for (int s = 0; s < NSUB; ++s)
                acc[s][tile] = mfma16h(A[s], Bh, acc[s][tile]);
        }
        if (hasNext)
            *(half8*)(ldsB1 + ((ks+1) & 1)*2048 + t*8) = stg;
        __syncthreads();
    }

    const float* bias = isV ? bs1 : b1;
    _Float16* o = isV ? V : U;
    #pragma unroll
    for (int s = 0; s < NSUB; ++s) {
        #pragma unroll
        for (int tile = 0; tile < 4; ++tile) {
            int col = cbl*64 + tile*16 + (lane & 15);
            float bv = bias[col];
            #pragma unroll
            for (int r = 0; r < 4; ++r) {
                int m = row0 + (s*4 + w)*16 + (lane >> 4)*4 + r;
                if (m < n)
                    o[(size_t)m*512 + col] = (_Float16)tanhf(acc[s][tile][r] + bv);
            }
        }
    }
}

// ---------------------------------------------------------------------------
// k2 body: stage-2 + select + write h. cb<4: H1=tanh(U@W2+b2) (k2==0 rows);
// cb>=4: H2=tanh(V@Ws2+bs2) (k2==1 rows)
// ---------------------------------------------------------------------------
template<int NSUB>
__device__ __forceinline__ void k2_body(
    int rb, int cb, int start, int n,
    const _Float16* __restrict__ U, const _Float16* __restrict__ V,
    const int* __restrict__ kids,
    const _Float16* __restrict__ w2pk, const _Float16* __restrict__ ws2pk,
    const float* __restrict__ b2, const float* __restrict__ bs2,
    _Float16* __restrict__ hh)
{
    __shared__ __align__(16) _Float16 ldsB2[2*2048];
    const int t = threadIdx.x, lane = t & 63, w = t >> 6;
    const bool isSym = cb >= 4;
    const int cbl = isSym ? cb - 4 : cb;
    const _Float16* pk = (isSym ? ws2pk : w2pk) + (size_t)cbl * 16 * 2048;
    const _Float16* Asrc = isSym ? V : U;
    const int row0 = rb * NSUB * 64;

    f32x4 acc[NSUB][4];
    #pragma unroll
    for (int s = 0; s < NSUB; ++s)
        #pragma unroll
        for (int c = 0; c < 4; ++c) acc[s][c] = (f32x4){0.f,0.f,0.f,0.f};

    *(half8*)(ldsB2 + t*8) = *(const half8*)(pk + (size_t)t*8);
    __syncthreads();

    for (int ks = 0; ks < 16; ++ks) {
        const bool hasNext = ks + 1 < 16;
        half8 stg;
        if (hasNext) stg = *(const half8*)(pk + (size_t)(ks+1)*2048 + (size_t)t*8);
        half8 A[NSUB];
        #pragma unroll
        for (int s = 0; s < NSUB; ++s) {
            int m = row0 + (s*4 + w)*16 + (lane & 15);
            if (m >= n) m = n - 1;
            A[s] = *(const half8*)(Asrc + (size_t)m*512 + (size_t)ks*32 + ((lane >> 4)*8));
        }
        const _Float16* lb = ldsB2 + (ks & 1)*2048;
        #pragma unroll
        for (int tile = 0; tile < 4; ++tile) {
            half8 Bh = *(const half8*)(lb + tile*512 + lane*8);
            #pragma unroll
            for (int s = 0; s < NSUB; ++s)
                acc[s][tile] = mfma16h(A[s], Bh, acc[s][tile]);
        }
        if (hasNext)
            *(half8*)(ldsB2 + ((ks+1) & 1)*2048 + t*8) = stg;
        __syncthreads();
    }

    const float* bias = isSym ? bs2 : b2;
    const int want = isSym ? 1 : 0;
    #pragma unroll
    for (int s = 0; s < NSUB; ++s) {
        #pragma unroll
        for (int tile = 0; tile < 4; ++tile) {
            int col = cbl*64 + tile*16 + (lane & 15);
            float bv = bias[col];
            #pragma unroll
            for (int r = 0; r < 4; ++r) {
                int m = row0 + (s*4 + w)*16 + (lane >> 4)*4 + r;
                if (m < n && kids[3*(start + m) + 2] == want)
                    hh[(size_t)(start + m)*256 + col] = (_Float16)tanhf(acc[s][tile][r] + bv);
            }
        }
    }
}

template<int NSUB>
__global__ __launch_bounds__(256) void k1_kernel(
    const _Float16* __restrict__ hh, const float* __restrict__ param,
    const _Float16* __restrict__ wcatpk, const _Float16* __restrict__ wscatpk,
    const float* __restrict__ b1, const float* __restrict__ bs1,
    _Float16* __restrict__ U, _Float16* __restrict__ V, int start, int n)
{
    k1_body<NSUB>(blockIdx.x, blockIdx.y, start, n, hh, param, wcatpk, wscatpk, b1, bs1, U, V);
}

template<int NSUB>
__global__ __launch_bounds__(256) void k2_kernel(
    const _Float16* __restrict__ U, const _Float16* __restrict__ V,
    const int* __restrict__ kids,
    const _Float16* __restrict__ w2pk, const _Float16* __restrict__ ws2pk,
    const float* __restrict__ b2, const float* __restrict__ bs2,
    _Float16* __restrict__ hh, int start, int n)
{
    k2_body<NSUB>(blockIdx.x, blockIdx.y, start, n, U, V, kids, w2pk, ws2pk, b2, bs2, hh);
}

// ---------------------------------------------------------------------------
// Grid-wide barrier (device-scope): release fence + atomic arrive + acquire spin
// ---------------------------------------------------------------------------
__device__ __forceinline__ void gbar(unsigned* bar, unsigned target)
{
    __syncthreads();
    if (threadIdx.x == 0) {
        __threadfence();   // release: make U/V/h stores visible device-wide
        __hip_atomic_fetch_add(bar, 1u, __ATOMIC_RELEASE, __HIP_MEMORY_SCOPE_AGENT);
        while (__hip_atomic_load(bar, __ATOMIC_ACQUIRE, __HIP_MEMORY_SCOPE_AGENT) < target)
            __builtin_amdgcn_s_sleep(2);
    }
    __syncthreads();
    __threadfence();       // acquire side for all threads: invalidate stale lines
}

// ---------------------------------------------------------------------------
// Tail: all levels n<=512 in one persistent kernel. Grid must be co-resident
// (128 blocks << 256 CUs). Two phases per level, grid barrier between.
// ---------------------------------------------------------------------------
__global__ __launch_bounds__(256) void tail_kernel(
    _Float16* __restrict__ hh, const float* __restrict__ param,
    const _Float16* __restrict__ wcatpk, const _Float16* __restrict__ wscatpk,
    const float* __restrict__ b1, const float* __restrict__ bs1,
    _Float16* __restrict__ U, _Float16* __restrict__ V,
    const int* __restrict__ kids,
    const _Float16* __restrict__ w2pk, const _Float16* __restrict__ ws2pk,
    const float* __restrict__ b2, const float* __restrict__ bs2,
    unsigned* __restrict__ bar)
{
    const int G = gridDim.x;
    unsigned tgt = 0;
    int start = LEAF + 8192 + 4096 + 2048 + 1024;   // = 31744, first tail level n=512
    for (int n = 512; n >= 1; n >>= 1) {
        int rt = (n + 63) >> 6;
        int J1 = rt * 16;
        for (int j = blockIdx.x; j < J1; j += G)
            k1_body<1>(j >> 4, j & 15, start, n, hh, param, wcatpk, wscatpk, b1, bs1, U, V);
        tgt += G; gbar(bar, tgt);
        int J2 = rt * 8;
        for (int j = blockIdx.x; j < J2; j += G)
            k2_body<1>(j >> 3, j & 7, start, n, U, V, kids, w2pk, ws2pk, b2, bs2, hh);
        if (n > 1) { tgt += G; gbar(bar, tgt); }
        start += n;
    }
}

__global__ void final_kernel(const _Float16* __restrict__ hh, float* __restrict__ out)
{
    int c = threadIdx.x;
    out[c] = (float)hh[(size_t)(NNODE - 1)*256 + c];
}

extern "C" void kernel_launch(void* const* d_in, const int* in_sizes, int n_in,
                              void* d_out, int out_size, void* d_ws, size_t ws_size,
                              hipStream_t stream) {
    const int*   kids  = (const int*)  d_in[0];
    const float* shape = (const float*)d_in[1];
    const float* param = (const float*)d_in[2];
    const float* Wb    = (const float*)d_in[3];
    const float* bb    = (const float*)d_in[4];
    const float* Wl    = (const float*)d_in[5];
    const float* Wr    = (const float*)d_in[6];
    const float* b1    = (const float*)d_in[7];
    const float* W2    = (const float*)d_in[8];
    const float* b2    = (const float*)d_in[9];
    const float* Wsl   = (const float*)d_in[10];
    const float* Wsr   = (const float*)d_in[11];
    const float* bs1   = (const float*)d_in[12];
    const float* Ws2   = (const float*)d_in[13];
    const float* bs2   = (const float*)d_in[14];
    float* out = (float*)d_out;

    char* ws = (char*)d_ws;
    _Float16* hh      = (_Float16*)(ws + 0);          // NNODE*256*2B = 16.8MB
    _Float16* U       = (_Float16*)(ws + 16777216);   // 8192*512*2B = 8.4MB
    _Float16* V       = (_Float16*)(ws + 25165824);   // 8.4MB
    _Float16* wcatpk  = (_Float16*)(ws + 33554432);   // 512KB
    _Float16* wscatpk = (_Float16*)(ws + 34078720);   // 320KB
    _Float16* w2pk    = (_Float16*)(ws + 34406400);   // 256KB
    _Float16* ws2pk   = (_Float16*)(ws + 34668544);   // 256KB
    unsigned* bar     = (unsigned*)(ws + 34930688);

    hipMemsetAsync(bar, 0, 256, stream);

    pack_kernel<<<1024, 256, 0, stream>>>(Wl,  Wr,  256, 512, 16, wcatpk,  262144);
    pack_kernel<<< 640, 256, 0, stream>>>(Wsl, Wsr, 256, 512, 10, wscatpk, 163840);
    pack_kernel<<< 512, 256, 0, stream>>>(W2,  W2,  512, 256, 16, w2pk,    131072);
    pack_kernel<<< 512, 256, 0, stream>>>(Ws2, Ws2, 512, 256, 16, ws2pk,   131072);

    leaf_kernel<<<LEAF/16, 256, 0, stream>>>(shape, Wb, bb, hh);

    int start = LEAF;
    for (int n = 8192; n >= 1024; n >>= 1) {
        if (n == 8192) {
            k1_kernel<2><<<dim3(n/128, 16), 256, 0, stream>>>(hh, param, wcatpk, wscatpk,
                                                              b1, bs1, U, V, start, n);
        } else {
            k1_kernel<1><<<dim3(n/64, 16), 256, 0, stream>>>(hh, param, wcatpk, wscatpk,
                                                             b1, bs1, U, V, start, n);
        }
        k2_kernel<1><<<dim3(n/64, 8), 256, 0, stream>>>(U, V, kids, w2pk, ws2pk,
                                                        b2, bs2, hh, start, n);
        start += n;
    }

    tail_kernel<<<128, 256, 0, stream>>>(hh, param, wcatpk, wscatpk, b1, bs1,
                                         U, V, kids, w2pk, ws2pk, b2, bs2, bar);

    final_kernel<<<1, 256, 0, stream>>>(hh, out);
}

// Round 6
// 414.064 us; speedup vs baseline: 2.0002x; 2.0002x over previous
//
#include <hip/hip_runtime.h>

#define LEAF   16384
#define NNODE  (2*LEAF-1)
#define LATENT 256
#define HIDDEN 512
#define SYM    64
#define BOX    128

using half8 = __attribute__((ext_vector_type(8))) _Float16;
using f32x4 = __attribute__((ext_vector_type(4))) float;

__device__ __forceinline__ f32x4 mfma16h(half8 a, half8 b, f32x4 c){
    return __builtin_amdgcn_mfma_f32_16x16x32_f16(a, b, c, 0, 0, 0);
}

// ---------------------------------------------------------------------------
// Weight pack (fp16, MFMA B-fragment order):
// pk[cb][ks][tile][lane][j]; k = ks*32+(lane>>4)*8+j; col = cb*64+tile*16+(lane&15)
// ---------------------------------------------------------------------------
__global__ void pack_kernel(const float* __restrict__ A, const float* __restrict__ B,
                            int Ksplit, int N, int KS, _Float16* __restrict__ pk, int total)
{
    int t = blockIdx.x*256 + threadIdx.x;
    if (t >= total) return;
    int j = t & 7, l = (t>>3)&63, tile = (t>>9)&3;
    int rest = t >> 11;
    int ks = rest % KS, cb = rest / KS;
    int k   = ks*32 + ((l>>4)*8) + j;
    int col = cb*64 + tile*16 + (l&15);
    float wv = (k < Ksplit) ? A[(size_t)k*N + col] : B[(size_t)(k-Ksplit)*N + col];
    pk[((size_t)(cb*KS + ks)*4 + tile)*512 + (size_t)l*8 + j] = (_Float16)wv;
}

// ---------------------------------------------------------------------------
// Leaf: h[r][c] = tanh(sum_k shape[k][r]*Wb[k][c] + bb[c]) -> fp16
// ---------------------------------------------------------------------------
__global__ __launch_bounds__(256) void leaf_kernel(
    const float* __restrict__ shape, const float* __restrict__ Wb,
    const float* __restrict__ bb, _Float16* __restrict__ hh)
{
    __shared__ float Xs[16][132];
    const int r0 = blockIdx.x * 16;
    const int t  = threadIdx.x;
    for (int it = 0; it < 2; ++it) {
        int task = t + it * 256;
        int r  = task & 15;
        int kg = task >> 4;
        #pragma unroll
        for (int j = 0; j < 4; ++j)
            Xs[r][4*kg + j] = shape[(size_t)(4*kg + j) * LEAF + r0 + r];
    }
    __syncthreads();
    float acc[16];
    #pragma unroll
    for (int r = 0; r < 16; ++r) acc[r] = 0.f;
    const int c = t;
    for (int k = 0; k < BOX; k += 4) {
        float w0 = Wb[(k+0)*LATENT + c];
        float w1 = Wb[(k+1)*LATENT + c];
        float w2 = Wb[(k+2)*LATENT + c];
        float w3 = Wb[(k+3)*LATENT + c];
        #pragma unroll
        for (int r = 0; r < 16; ++r) {
            float4 x = *reinterpret_cast<const float4*>(&Xs[r][k]);
            acc[r] = fmaf(x.x, w0, acc[r]);
            acc[r] = fmaf(x.y, w1, acc[r]);
            acc[r] = fmaf(x.z, w2, acc[r]);
            acc[r] = fmaf(x.w, w3, acc[r]);
        }
    }
    float bias = bb[c];
    #pragma unroll
    for (int r = 0; r < 16; ++r)
        hh[(size_t)(r0 + r) * LATENT + c] = (_Float16)tanhf(acc[r] + bias);
}

// ---------------------------------------------------------------------------
// k1 body (dispatch path, B streamed through LDS double-buffer)
// ---------------------------------------------------------------------------
template<int NSUB>
__device__ __forceinline__ void k1_body(
    int rb, int cb, int start, int n,
    const _Float16* __restrict__ hh, const float* __restrict__ param,
    const _Float16* __restrict__ wcatpk, const _Float16* __restrict__ wscatpk,
    const float* __restrict__ b1, const float* __restrict__ bs1,
    _Float16* __restrict__ U, _Float16* __restrict__ V)
{
    __shared__ __align__(16) _Float16 ldsB1[2*2048];
    const int t = threadIdx.x, lane = t & 63, w = t >> 6;
    const bool isV = cb >= 8;
    const int cbl = isV ? cb - 8 : cb;
    const int KS  = isV ? 10 : 16;
    const _Float16* pk = (isV ? wscatpk : wcatpk) + (size_t)cbl * KS * 2048;
    const int row0  = rb * NSUB * 64;
    const int cbase = 2 * (start - LEAF);

    f32x4 acc[NSUB][4];
    #pragma unroll
    for (int s = 0; s < NSUB; ++s)
        #pragma unroll
        for (int c = 0; c < 4; ++c) acc[s][c] = (f32x4){0.f,0.f,0.f,0.f};

    *(half8*)(ldsB1 + t*8) = *(const half8*)(pk + (size_t)t*8);
    __syncthreads();

    for (int ks = 0; ks < KS; ++ks) {
        const bool hasNext = ks + 1 < KS;
        half8 stg;
        if (hasNext) stg = *(const half8*)(pk + (size_t)(ks+1)*2048 + (size_t)t*8);
        half8 A[NSUB];
        #pragma unroll
        for (int s = 0; s < NSUB; ++s) {
            int m = row0 + (s*4 + w)*16 + (lane & 15);
            if (m >= n) m = n - 1;
            if (!isV || ks < 8) {
                int node = cbase + 2*m + (ks >= 8 ? 1 : 0);
                A[s] = *(const half8*)(hh + (size_t)node*256 + (size_t)(ks & 7)*32 + ((lane >> 4)*8));
            } else {
                const float* pp = param + (size_t)(cbase + 2*m)*64 + (ks - 8)*32 + (lane >> 4)*8;
                float4 p0 = *(const float4*)pp;
                float4 p1 = *(const float4*)(pp + 4);
                A[s][0]=(_Float16)p0.x; A[s][1]=(_Float16)p0.y; A[s][2]=(_Float16)p0.z; A[s][3]=(_Float16)p0.w;
                A[s][4]=(_Float16)p1.x; A[s][5]=(_Float16)p1.y; A[s][6]=(_Float16)p1.z; A[s][7]=(_Float16)p1.w;
            }
        }
        const _Float16* lb = ldsB1 + (ks & 1)*2048;
        #pragma unroll
        for (int tile = 0; tile < 4; ++tile) {
            half8 Bh = *(const half8*)(lb + tile*512 + lane*8);
            #pragma unroll
            for (int s = 0; s < NSUB; ++s)
                acc[s][tile] = mfma16h(A[s], Bh, acc[s][tile]);
        }
        if (hasNext)
            *(half8*)(ldsB1 + ((ks+1) & 1)*2048 + t*8) = stg;
        __syncthreads();
    }

    const float* bias = isV ? bs1 : b1;
    _Float16* o = isV ? V : U;
    #pragma unroll
    for (int s = 0; s < NSUB; ++s) {
        #pragma unroll
        for (int tile = 0; tile < 4; ++tile) {
            int col = cbl*64 + tile*16 + (lane & 15);
            float bv = bias[col];
            #pragma unroll
            for (int r = 0; r < 4; ++r) {
                int m = row0 + (s*4 + w)*16 + (lane >> 4)*4 + r;
                if (m < n)
                    o[(size_t)m*512 + col] = (_Float16)tanhf(acc[s][tile][r] + bv);
            }
        }
    }
}

// ---------------------------------------------------------------------------
// k2 body (dispatch path)
// ---------------------------------------------------------------------------
template<int NSUB>
__device__ __forceinline__ void k2_body(
    int rb, int cb, int start, int n,
    const _Float16* __restrict__ U, const _Float16* __restrict__ V,
    const int* __restrict__ kids,
    const _Float16* __restrict__ w2pk, const _Float16* __restrict__ ws2pk,
    const float* __restrict__ b2, const float* __restrict__ bs2,
    _Float16* __restrict__ hh)
{
    __shared__ __align__(16) _Float16 ldsB2[2*2048];
    const int t = threadIdx.x, lane = t & 63, w = t >> 6;
    const bool isSym = cb >= 4;
    const int cbl = isSym ? cb - 4 : cb;
    const _Float16* pk = (isSym ? ws2pk : w2pk) + (size_t)cbl * 16 * 2048;
    const _Float16* Asrc = isSym ? V : U;
    const int row0 = rb * NSUB * 64;

    f32x4 acc[NSUB][4];
    #pragma unroll
    for (int s = 0; s < NSUB; ++s)
        #pragma unroll
        for (int c = 0; c < 4; ++c) acc[s][c] = (f32x4){0.f,0.f,0.f,0.f};

    *(half8*)(ldsB2 + t*8) = *(const half8*)(pk + (size_t)t*8);
    __syncthreads();

    for (int ks = 0; ks < 16; ++ks) {
        const bool hasNext = ks + 1 < 16;
        half8 stg;
        if (hasNext) stg = *(const half8*)(pk + (size_t)(ks+1)*2048 + (size_t)t*8);
        half8 A[NSUB];
        #pragma unroll
        for (int s = 0; s < NSUB; ++s) {
            int m = row0 + (s*4 + w)*16 + (lane & 15);
            if (m >= n) m = n - 1;
            A[s] = *(const half8*)(Asrc + (size_t)m*512 + (size_t)ks*32 + ((lane >> 4)*8));
        }
        const _Float16* lb = ldsB2 + (ks & 1)*2048;
        #pragma unroll
        for (int tile = 0; tile < 4; ++tile) {
            half8 Bh = *(const half8*)(lb + tile*512 + lane*8);
            #pragma unroll
            for (int s = 0; s < NSUB; ++s)
                acc[s][tile] = mfma16h(A[s], Bh, acc[s][tile]);
        }
        if (hasNext)
            *(half8*)(ldsB2 + ((ks+1) & 1)*2048 + t*8) = stg;
        __syncthreads();
    }

    const float* bias = isSym ? bs2 : b2;
    const int want = isSym ? 1 : 0;
    #pragma unroll
    for (int s = 0; s < NSUB; ++s) {
        #pragma unroll
        for (int tile = 0; tile < 4; ++tile) {
            int col = cbl*64 + tile*16 + (lane & 15);
            float bv = bias[col];
            #pragma unroll
            for (int r = 0; r < 4; ++r) {
                int m = row0 + (s*4 + w)*16 + (lane >> 4)*4 + r;
                if (m < n && kids[3*(start + m) + 2] == want)
                    hh[(size_t)(start + m)*256 + col] = (_Float16)tanhf(acc[s][tile][r] + bv);
            }
        }
    }
}

template<int NSUB>
__global__ __launch_bounds__(256) void k1_kernel(
    const _Float16* __restrict__ hh, const float* __restrict__ param,
    const _Float16* __restrict__ wcatpk, const _Float16* __restrict__ wscatpk,
    const float* __restrict__ b1, const float* __restrict__ bs1,
    _Float16* __restrict__ U, _Float16* __restrict__ V, int start, int n)
{
    k1_body<NSUB>(blockIdx.x, blockIdx.y, start, n, hh, param, wcatpk, wscatpk, b1, bs1, U, V);
}

template<int NSUB>
__global__ __launch_bounds__(256) void k2_kernel(
    const _Float16* __restrict__ U, const _Float16* __restrict__ V,
    const int* __restrict__ kids,
    const _Float16* __restrict__ w2pk, const _Float16* __restrict__ ws2pk,
    const float* __restrict__ b2, const float* __restrict__ bs2,
    _Float16* __restrict__ hh, int start, int n)
{
    k2_body<NSUB>(blockIdx.x, blockIdx.y, start, n, U, V, kids, w2pk, ws2pk, b2, bs2, hh);
}

// ---------------------------------------------------------------------------
// Tail bodies: B-operand pinned in LDS (wlds), NO per-K-step syncthreads.
// ---------------------------------------------------------------------------
__device__ __forceinline__ void k1_tail(
    int rb, int cb, int start, int n,
    const _Float16* __restrict__ hh, const float* __restrict__ param,
    const _Float16* wlds,
    const float* __restrict__ b1, const float* __restrict__ bs1,
    _Float16* __restrict__ U, _Float16* __restrict__ V)
{
    const int t = threadIdx.x, lane = t & 63, w = t >> 6;
    const bool isV = cb >= 8;
    const int cbl = isV ? cb - 8 : cb;
    const int KS  = isV ? 10 : 16;
    const int row0  = rb * 64;
    const int cbase = 2 * (start - LEAF);

    f32x4 acc[4];
    #pragma unroll
    for (int c = 0; c < 4; ++c) acc[c] = (f32x4){0.f,0.f,0.f,0.f};

    int m = row0 + w*16 + (lane & 15);
    if (m >= n) m = n - 1;

    for (int ks = 0; ks < KS; ++ks) {
        half8 A;
        if (!isV || ks < 8) {
            int node = cbase + 2*m + (ks >= 8 ? 1 : 0);
            A = *(const half8*)(hh + (size_t)node*256 + (size_t)(ks & 7)*32 + ((lane >> 4)*8));
        } else {
            const float* pp = param + (size_t)(cbase + 2*m)*64 + (ks - 8)*32 + (lane >> 4)*8;
            float4 p0 = *(const float4*)pp;
            float4 p1 = *(const float4*)(pp + 4);
            A[0]=(_Float16)p0.x; A[1]=(_Float16)p0.y; A[2]=(_Float16)p0.z; A[3]=(_Float16)p0.w;
            A[4]=(_Float16)p1.x; A[5]=(_Float16)p1.y; A[6]=(_Float16)p1.z; A[7]=(_Float16)p1.w;
        }
        const _Float16* lb = wlds + ks*2048;
        #pragma unroll
        for (int tile = 0; tile < 4; ++tile) {
            half8 Bh = *(const half8*)(lb + tile*512 + lane*8);
            acc[tile] = mfma16h(A, Bh, acc[tile]);
        }
    }

    const float* bias = isV ? bs1 : b1;
    _Float16* o = isV ? V : U;
    #pragma unroll
    for (int tile = 0; tile < 4; ++tile) {
        int col = cbl*64 + tile*16 + (lane & 15);
        float bv = bias[col];
        #pragma unroll
        for (int r = 0; r < 4; ++r) {
            int mm = row0 + w*16 + (lane >> 4)*4 + r;
            if (mm < n)
                o[(size_t)mm*512 + col] = (_Float16)tanhf(acc[tile][r] + bv);
        }
    }
}

__device__ __forceinline__ void k2_tail(
    int rb, int cb, int start, int n,
    const _Float16* __restrict__ U, const _Float16* __restrict__ V,
    const int* __restrict__ kids,
    const _Float16* wlds,
    const float* __restrict__ b2, const float* __restrict__ bs2,
    _Float16* __restrict__ hh)
{
    const int t = threadIdx.x, lane = t & 63, w = t >> 6;
    const bool isSym = cb >= 4;
    const int cbl = isSym ? cb - 4 : cb;
    const _Float16* Asrc = isSym ? V : U;
    const int row0 = rb * 64;

    f32x4 acc[4];
    #pragma unroll
    for (int c = 0; c < 4; ++c) acc[c] = (f32x4){0.f,0.f,0.f,0.f};

    int m = row0 + w*16 + (lane & 15);
    if (m >= n) m = n - 1;

    for (int ks = 0; ks < 16; ++ks) {
        half8 A = *(const half8*)(Asrc + (size_t)m*512 + (size_t)ks*32 + ((lane >> 4)*8));
        const _Float16* lb = wlds + ks*2048;
        #pragma unroll
        for (int tile = 0; tile < 4; ++tile) {
            half8 Bh = *(const half8*)(lb + tile*512 + lane*8);
            acc[tile] = mfma16h(A, Bh, acc[tile]);
        }
    }

    const float* bias = isSym ? bs2 : b2;
    const int want = isSym ? 1 : 0;
    #pragma unroll
    for (int tile = 0; tile < 4; ++tile) {
        int col = cbl*64 + tile*16 + (lane & 15);
        float bv = bias[col];
        #pragma unroll
        for (int r = 0; r < 4; ++r) {
            int mm = row0 + w*16 + (lane >> 4)*4 + r;
            if (mm < n && kids[3*(start + mm) + 2] == want)
                hh[(size_t)(start + mm)*256 + col] = (_Float16)tanhf(acc[tile][r] + bv);
        }
    }
}

// ---------------------------------------------------------------------------
// Grid-wide barrier (device-scope): release fence + atomic arrive + acquire spin
// ---------------------------------------------------------------------------
__device__ __forceinline__ void gbar(unsigned* bar, unsigned target)
{
    __syncthreads();
    if (threadIdx.x == 0) {
        __threadfence();   // release
        __hip_atomic_fetch_add(bar, 1u, __ATOMIC_RELEASE, __HIP_MEMORY_SCOPE_AGENT);
        while (__hip_atomic_load(bar, __ATOMIC_ACQUIRE, __HIP_MEMORY_SCOPE_AGENT) < target)
            __builtin_amdgcn_s_sleep(2);
    }
    __syncthreads();
    __threadfence();       // acquire
}

// ---------------------------------------------------------------------------
// Tail: levels n<=256 in one persistent kernel, 24 blocks.
// Blocks 0-15: k1 col-slices (weights in LDS). Blocks 16-23: k2 col-slices.
// Weights loaded into LDS ONCE -> immune to barrier cache invalidations.
// ---------------------------------------------------------------------------
__global__ __launch_bounds__(256) void tail_kernel(
    _Float16* __restrict__ hh, const float* __restrict__ param,
    const _Float16* __restrict__ wcatpk, const _Float16* __restrict__ wscatpk,
    const float* __restrict__ b1, const float* __restrict__ bs1,
    _Float16* __restrict__ U, _Float16* __restrict__ V,
    const int* __restrict__ kids,
    const _Float16* __restrict__ w2pk, const _Float16* __restrict__ ws2pk,
    const float* __restrict__ b2, const float* __restrict__ bs2,
    unsigned* __restrict__ bar)
{
    __shared__ __align__(16) _Float16 wlds[16*2048];   // 64 KB
    const int b = blockIdx.x;          // 0..23
    const int t = threadIdx.x;

    // one-time weight slice preload
    const _Float16* src;
    int nh;
    if (b < 8)       { src = wcatpk  + (size_t)b*16*2048;      nh = 16*2048/8; }
    else if (b < 16) { src = wscatpk + (size_t)(b-8)*10*2048;  nh = 10*2048/8; }
    else if (b < 20) { src = w2pk    + (size_t)(b-16)*16*2048; nh = 16*2048/8; }
    else             { src = ws2pk   + (size_t)(b-20)*16*2048; nh = 16*2048/8; }
    for (int i = t; i < nh; i += 256)
        *(half8*)(wlds + (size_t)i*8) = *(const half8*)(src + (size_t)i*8);
    __syncthreads();

    const unsigned G = gridDim.x;      // 24
    unsigned tgt = 0;
    int start = LEAF + 8192 + 4096 + 2048 + 1024 + 512;   // 32256, first level n=256
    for (int n = 256; n >= 1; n >>= 1) {
        int rt = (n + 63) >> 6;
        if (b < 16) {
            for (int r = 0; r < rt; ++r)
                k1_tail(r, b, start, n, hh, param, wlds, b1, bs1, U, V);
        }
        tgt += G; gbar(bar, tgt);
        if (b >= 16) {
            for (int r = 0; r < rt; ++r)
                k2_tail(r, b - 16, start, n, U, V, kids, wlds, b2, bs2, hh);
        }
        if (n > 1) { tgt += G; gbar(bar, tgt); }
        start += n;
    }
}

__global__ void final_kernel(const _Float16* __restrict__ hh, float* __restrict__ out)
{
    int c = threadIdx.x;
    out[c] = (float)hh[(size_t)(NNODE - 1)*256 + c];
}

extern "C" void kernel_launch(void* const* d_in, const int* in_sizes, int n_in,
                              void* d_out, int out_size, void* d_ws, size_t ws_size,
                              hipStream_t stream) {
    const int*   kids  = (const int*)  d_in[0];
    const float* shape = (const float*)d_in[1];
    const float* param = (const float*)d_in[2];
    const float* Wb    = (const float*)d_in[3];
    const float* bb    = (const float*)d_in[4];
    const float* Wl    = (const float*)d_in[5];
    const float* Wr    = (const float*)d_in[6];
    const float* b1    = (const float*)d_in[7];
    const float* W2    = (const float*)d_in[8];
    const float* b2    = (const float*)d_in[9];
    const float* Wsl   = (const float*)d_in[10];
    const float* Wsr   = (const float*)d_in[11];
    const float* bs1   = (const float*)d_in[12];
    const float* Ws2   = (const float*)d_in[13];
    const float* bs2   = (const float*)d_in[14];
    float* out = (float*)d_out;

    char* ws = (char*)d_ws;
    _Float16* hh      = (_Float16*)(ws + 0);          // 16.8MB
    _Float16* U       = (_Float16*)(ws + 16777216);   // 8.4MB
    _Float16* V       = (_Float16*)(ws + 25165824);   // 8.4MB
    _Float16* wcatpk  = (_Float16*)(ws + 33554432);   // 512KB
    _Float16* wscatpk = (_Float16*)(ws + 34078720);   // 320KB
    _Float16* w2pk    = (_Float16*)(ws + 34406400);   // 256KB
    _Float16* ws2pk   = (_Float16*)(ws + 34668544);   // 256KB
    unsigned* bar     = (unsigned*)(ws + 34930688);

    hipMemsetAsync(bar, 0, 256, stream);

    pack_kernel<<<1024, 256, 0, stream>>>(Wl,  Wr,  256, 512, 16, wcatpk,  262144);
    pack_kernel<<< 640, 256, 0, stream>>>(Wsl, Wsr, 256, 512, 10, wscatpk, 163840);
    pack_kernel<<< 512, 256, 0, stream>>>(W2,  W2,  512, 256, 16, w2pk,    131072);
    pack_kernel<<< 512, 256, 0, stream>>>(Ws2, Ws2, 512, 256, 16, ws2pk,   131072);

    leaf_kernel<<<LEAF/16, 256, 0, stream>>>(shape, Wb, bb, hh);

    int start = LEAF;
    for (int n = 8192; n >= 512; n >>= 1) {
        if (n == 8192) {
            k1_kernel<2><<<dim3(n/128, 16), 256, 0, stream>>>(hh, param, wcatpk, wscatpk,
                                                              b1, bs1, U, V, start, n);
        } else {
            k1_kernel<1><<<dim3(n/64, 16), 256, 0, stream>>>(hh, param, wcatpk, wscatpk,
                                                             b1, bs1, U, V, start, n);
        }
        k2_kernel<1><<<dim3(n/64, 8), 256, 0, stream>>>(U, V, kids, w2pk, ws2pk,
                                                        b2, bs2, hh, start, n);
        start += n;
    }

    tail_kernel<<<24, 256, 0, stream>>>(hh, param, wcatpk, wscatpk, b1, bs1,
                                        U, V, kids, w2pk, ws2pk, b2, bs2, bar);

    final_kernel<<<1, 256, 0, stream>>>(hh, out);
}

// Round 7
// 360.969 us; speedup vs baseline: 2.2944x; 1.1471x over previous
//
#include <hip/hip_runtime.h>

#define LEAF   16384
#define NNODE  (2*LEAF-1)
#define LATENT 256
#define HIDDEN 512
#define SYM    64
#define BOX    128

using half8 = __attribute__((ext_vector_type(8))) _Float16;
using f32x4 = __attribute__((ext_vector_type(4))) float;

__device__ __forceinline__ f32x4 mfma16h(half8 a, half8 b, f32x4 c){
    return __builtin_amdgcn_mfma_f32_16x16x32_f16(a, b, c, 0, 0, 0);
}

// ---------------------------------------------------------------------------
// Weight pack (fp16, MFMA B-fragment order):
// pk[cb][ks][tile][lane][j]; k = ks*32+(lane>>4)*8+j; col = cb*64+tile*16+(lane&15)
// ---------------------------------------------------------------------------
__global__ void pack_kernel(const float* __restrict__ A, const float* __restrict__ B,
                            int Ksplit, int N, int KS, _Float16* __restrict__ pk, int total)
{
    int t = blockIdx.x*256 + threadIdx.x;
    if (t >= total) return;
    int j = t & 7, l = (t>>3)&63, tile = (t>>9)&3;
    int rest = t >> 11;
    int ks = rest % KS, cb = rest / KS;
    int k   = ks*32 + ((l>>4)*8) + j;
    int col = cb*64 + tile*16 + (l&15);
    float wv = (k < Ksplit) ? A[(size_t)k*N + col] : B[(size_t)(k-Ksplit)*N + col];
    pk[((size_t)(cb*KS + ks)*4 + tile)*512 + (size_t)l*8 + j] = (_Float16)wv;
}

// ---------------------------------------------------------------------------
// Leaf via MFMA: hh[m][c] = tanh(sum_k shape[k][m]*Wb[k][c] + bb[c])
// grid 256 blocks x 64 rows. A-frags straight from global (coalesced 64B segs).
// ---------------------------------------------------------------------------
__global__ __launch_bounds__(256) void leaf_mfma_kernel(
    const float* __restrict__ shape, const _Float16* __restrict__ wbpk,
    const float* __restrict__ bb, _Float16* __restrict__ hh)
{
    const int t = threadIdx.x, lane = t & 63, w = t >> 6;
    const int r0 = blockIdx.x * 64;
    const int m = r0 + w*16 + (lane & 15);

    half8 A[4];
    #pragma unroll
    for (int ks = 0; ks < 4; ++ks) {
        #pragma unroll
        for (int e = 0; e < 8; ++e) {
            int k = ks*32 + (lane >> 4)*8 + e;
            A[ks][e] = (_Float16)shape[(size_t)k*LEAF + m];
        }
    }

    for (int cb = 0; cb < 4; ++cb) {
        f32x4 acc[4];
        #pragma unroll
        for (int c = 0; c < 4; ++c) acc[c] = (f32x4){0.f,0.f,0.f,0.f};
        #pragma unroll
        for (int ks = 0; ks < 4; ++ks) {
            const _Float16* pb = wbpk + (size_t)((cb*4 + ks)*4)*512;
            #pragma unroll
            for (int tile = 0; tile < 4; ++tile) {
                half8 B = *(const half8*)(pb + tile*512 + lane*8);
                acc[tile] = mfma16h(A[ks], B, acc[tile]);
            }
        }
        #pragma unroll
        for (int tile = 0; tile < 4; ++tile) {
            int col = cb*64 + tile*16 + (lane & 15);
            float bv = bb[col];
            #pragma unroll
            for (int r = 0; r < 4; ++r) {
                int row = r0 + w*16 + (lane >> 4)*4 + r;
                hh[(size_t)row*256 + col] = (_Float16)tanhf(acc[tile][r] + bv);
            }
        }
    }
}

// ---------------------------------------------------------------------------
// k1 body (dispatch path, B streamed through LDS double-buffer)
// ---------------------------------------------------------------------------
template<int NSUB>
__device__ __forceinline__ void k1_body(
    int rb, int cb, int start, int n,
    const _Float16* __restrict__ hh, const float* __restrict__ param,
    const _Float16* __restrict__ wcatpk, const _Float16* __restrict__ wscatpk,
    const float* __restrict__ b1, const float* __restrict__ bs1,
    _Float16* __restrict__ U, _Float16* __restrict__ V)
{
    __shared__ __align__(16) _Float16 ldsB1[2*2048];
    const int t = threadIdx.x, lane = t & 63, w = t >> 6;
    const bool isV = cb >= 8;
    const int cbl = isV ? cb - 8 : cb;
    const int KS  = isV ? 10 : 16;
    const _Float16* pk = (isV ? wscatpk : wcatpk) + (size_t)cbl * KS * 2048;
    const int row0  = rb * NSUB * 64;
    const int cbase = 2 * (start - LEAF);

    f32x4 acc[NSUB][4];
    #pragma unroll
    for (int s = 0; s < NSUB; ++s)
        #pragma unroll
        for (int c = 0; c < 4; ++c) acc[s][c] = (f32x4){0.f,0.f,0.f,0.f};

    *(half8*)(ldsB1 + t*8) = *(const half8*)(pk + (size_t)t*8);
    __syncthreads();

    for (int ks = 0; ks < KS; ++ks) {
        const bool hasNext = ks + 1 < KS;
        half8 stg;
        if (hasNext) stg = *(const half8*)(pk + (size_t)(ks+1)*2048 + (size_t)t*8);
        half8 A[NSUB];
        #pragma unroll
        for (int s = 0; s < NSUB; ++s) {
            int m = row0 + (s*4 + w)*16 + (lane & 15);
            if (m >= n) m = n - 1;
            if (!isV || ks < 8) {
                int node = cbase + 2*m + (ks >= 8 ? 1 : 0);
                A[s] = *(const half8*)(hh + (size_t)node*256 + (size_t)(ks & 7)*32 + ((lane >> 4)*8));
            } else {
                const float* pp = param + (size_t)(cbase + 2*m)*64 + (ks - 8)*32 + (lane >> 4)*8;
                float4 p0 = *(const float4*)pp;
                float4 p1 = *(const float4*)(pp + 4);
                A[s][0]=(_Float16)p0.x; A[s][1]=(_Float16)p0.y; A[s][2]=(_Float16)p0.z; A[s][3]=(_Float16)p0.w;
                A[s][4]=(_Float16)p1.x; A[s][5]=(_Float16)p1.y; A[s][6]=(_Float16)p1.z; A[s][7]=(_Float16)p1.w;
            }
        }
        const _Float16* lb = ldsB1 + (ks & 1)*2048;
        #pragma unroll
        for (int tile = 0; tile < 4; ++tile) {
            half8 Bh = *(const half8*)(lb + tile*512 + lane*8);
            #pragma unroll
            for (int s = 0; s < NSUB; ++s)
                acc[s][tile] = mfma16h(A[s], Bh, acc[s][tile]);
        }
        if (hasNext)
            *(half8*)(ldsB1 + ((ks+1) & 1)*2048 + t*8) = stg;
        __syncthreads();
    }

    const float* bias = isV ? bs1 : b1;
    _Float16* o = isV ? V : U;
    #pragma unroll
    for (int s = 0; s < NSUB; ++s) {
        #pragma unroll
        for (int tile = 0; tile < 4; ++tile) {
            int col = cbl*64 + tile*16 + (lane & 15);
            float bv = bias[col];
            #pragma unroll
            for (int r = 0; r < 4; ++r) {
                int m = row0 + (s*4 + w)*16 + (lane >> 4)*4 + r;
                if (m < n)
                    o[(size_t)m*512 + col] = (_Float16)tanhf(acc[s][tile][r] + bv);
            }
        }
    }
}

// ---------------------------------------------------------------------------
// k2 body (dispatch path)
// ---------------------------------------------------------------------------
template<int NSUB>
__device__ __forceinline__ void k2_body(
    int rb, int cb, int start, int n,
    const _Float16* __restrict__ U, const _Float16* __restrict__ V,
    const int* __restrict__ kids,
    const _Float16* __restrict__ w2pk, const _Float16* __restrict__ ws2pk,
    const float* __restrict__ b2, const float* __restrict__ bs2,
    _Float16* __restrict__ hh)
{
    __shared__ __align__(16) _Float16 ldsB2[2*2048];
    const int t = threadIdx.x, lane = t & 63, w = t >> 6;
    const bool isSym = cb >= 4;
    const int cbl = isSym ? cb - 4 : cb;
    const _Float16* pk = (isSym ? ws2pk : w2pk) + (size_t)cbl * 16 * 2048;
    const _Float16* Asrc = isSym ? V : U;
    const int row0 = rb * NSUB * 64;

    f32x4 acc[NSUB][4];
    #pragma unroll
    for (int s = 0; s < NSUB; ++s)
        #pragma unroll
        for (int c = 0; c < 4; ++c) acc[s][c] = (f32x4){0.f,0.f,0.f,0.f};

    *(half8*)(ldsB2 + t*8) = *(const half8*)(pk + (size_t)t*8);
    __syncthreads();

    for (int ks = 0; ks < 16; ++ks) {
        const bool hasNext = ks + 1 < 16;
        half8 stg;
        if (hasNext) stg = *(const half8*)(pk + (size_t)(ks+1)*2048 + (size_t)t*8);
        half8 A[NSUB];
        #pragma unroll
        for (int s = 0; s < NSUB; ++s) {
            int m = row0 + (s*4 + w)*16 + (lane & 15);
            if (m >= n) m = n - 1;
            A[s] = *(const half8*)(Asrc + (size_t)m*512 + (size_t)ks*32 + ((lane >> 4)*8));
        }
        const _Float16* lb = ldsB2 + (ks & 1)*2048;
        #pragma unroll
        for (int tile = 0; tile < 4; ++tile) {
            half8 Bh = *(const half8*)(lb + tile*512 + lane*8);
            #pragma unroll
            for (int s = 0; s < NSUB; ++s)
                acc[s][tile] = mfma16h(A[s], Bh, acc[s][tile]);
        }
        if (hasNext)
            *(half8*)(ldsB2 + ((ks+1) & 1)*2048 + t*8) = stg;
        __syncthreads();
    }

    const float* bias = isSym ? bs2 : b2;
    const int want = isSym ? 1 : 0;
    #pragma unroll
    for (int s = 0; s < NSUB; ++s) {
        #pragma unroll
        for (int tile = 0; tile < 4; ++tile) {
            int col = cbl*64 + tile*16 + (lane & 15);
            float bv = bias[col];
            #pragma unroll
            for (int r = 0; r < 4; ++r) {
                int m = row0 + (s*4 + w)*16 + (lane >> 4)*4 + r;
                if (m < n && kids[3*(start + m) + 2] == want)
                    hh[(size_t)(start + m)*256 + col] = (_Float16)tanhf(acc[s][tile][r] + bv);
            }
        }
    }
}

template<int NSUB>
__global__ __launch_bounds__(256) void k1_kernel(
    const _Float16* __restrict__ hh, const float* __restrict__ param,
    const _Float16* __restrict__ wcatpk, const _Float16* __restrict__ wscatpk,
    const float* __restrict__ b1, const float* __restrict__ bs1,
    _Float16* __restrict__ U, _Float16* __restrict__ V, int start, int n)
{
    k1_body<NSUB>(blockIdx.x, blockIdx.y, start, n, hh, param, wcatpk, wscatpk, b1, bs1, U, V);
}

template<int NSUB>
__global__ __launch_bounds__(256) void k2_kernel(
    const _Float16* __restrict__ U, const _Float16* __restrict__ V,
    const int* __restrict__ kids,
    const _Float16* __restrict__ w2pk, const _Float16* __restrict__ ws2pk,
    const float* __restrict__ b2, const float* __restrict__ bs2,
    _Float16* __restrict__ hh, int start, int n)
{
    k2_body<NSUB>(blockIdx.x, blockIdx.y, start, n, U, V, kids, w2pk, ws2pk, b2, bs2, hh);
}

// ---------------------------------------------------------------------------
// Tail bodies: B-operand pinned in LDS (wlds), no per-K-step syncthreads.
// ---------------------------------------------------------------------------
__device__ __forceinline__ void k1_tail(
    int rb, int cb, int start, int n,
    const _Float16* __restrict__ hh, const float* __restrict__ param,
    const _Float16* wlds,
    const float* __restrict__ b1, const float* __restrict__ bs1,
    _Float16* __restrict__ U, _Float16* __restrict__ V)
{
    const int t = threadIdx.x, lane = t & 63, w = t >> 6;
    const bool isV = cb >= 8;
    const int cbl = isV ? cb - 8 : cb;
    const int KS  = isV ? 10 : 16;
    const int row0  = rb * 64;
    const int cbase = 2 * (start - LEAF);

    f32x4 acc[4];
    #pragma unroll
    for (int c = 0; c < 4; ++c) acc[c] = (f32x4){0.f,0.f,0.f,0.f};

    int m = row0 + w*16 + (lane & 15);
    if (m >= n) m = n - 1;

    for (int ks = 0; ks < KS; ++ks) {
        half8 A;
        if (!isV || ks < 8) {
            int node = cbase + 2*m + (ks >= 8 ? 1 : 0);
            A = *(const half8*)(hh + (size_t)node*256 + (size_t)(ks & 7)*32 + ((lane >> 4)*8));
        } else {
            const float* pp = param + (size_t)(cbase + 2*m)*64 + (ks - 8)*32 + (lane >> 4)*8;
            float4 p0 = *(const float4*)pp;
            float4 p1 = *(const float4*)(pp + 4);
            A[0]=(_Float16)p0.x; A[1]=(_Float16)p0.y; A[2]=(_Float16)p0.z; A[3]=(_Float16)p0.w;
            A[4]=(_Float16)p1.x; A[5]=(_Float16)p1.y; A[6]=(_Float16)p1.z; A[7]=(_Float16)p1.w;
        }
        const _Float16* lb = wlds + ks*2048;
        #pragma unroll
        for (int tile = 0; tile < 4; ++tile) {
            half8 Bh = *(const half8*)(lb + tile*512 + lane*8);
            acc[tile] = mfma16h(A, Bh, acc[tile]);
        }
    }

    const float* bias = isV ? bs1 : b1;
    _Float16* o = isV ? V : U;
    #pragma unroll
    for (int tile = 0; tile < 4; ++tile) {
        int col = cbl*64 + tile*16 + (lane & 15);
        float bv = bias[col];
        #pragma unroll
        for (int r = 0; r < 4; ++r) {
            int mm = row0 + w*16 + (lane >> 4)*4 + r;
            if (mm < n)
                o[(size_t)mm*512 + col] = (_Float16)tanhf(acc[tile][r] + bv);
        }
    }
}

__device__ __forceinline__ void k2_tail(
    int rb, int cb, int start, int n,
    const _Float16* __restrict__ U, const _Float16* __restrict__ V,
    const int* __restrict__ kids,
    const _Float16* wlds,
    const float* __restrict__ b2, const float* __restrict__ bs2,
    _Float16* __restrict__ hh)
{
    const int t = threadIdx.x, lane = t & 63, w = t >> 6;
    const bool isSym = cb >= 4;
    const int cbl = isSym ? cb - 4 : cb;
    const _Float16* Asrc = isSym ? V : U;
    const int row0 = rb * 64;

    f32x4 acc[4];
    #pragma unroll
    for (int c = 0; c < 4; ++c) acc[c] = (f32x4){0.f,0.f,0.f,0.f};

    int m = row0 + w*16 + (lane & 15);
    if (m >= n) m = n - 1;

    for (int ks = 0; ks < 16; ++ks) {
        half8 A = *(const half8*)(Asrc + (size_t)m*512 + (size_t)ks*32 + ((lane >> 4)*8));
        const _Float16* lb = wlds + ks*2048;
        #pragma unroll
        for (int tile = 0; tile < 4; ++tile) {
            half8 Bh = *(const half8*)(lb + tile*512 + lane*8);
            acc[tile] = mfma16h(A, Bh, acc[tile]);
        }
    }

    const float* bias = isSym ? bs2 : b2;
    const int want = isSym ? 1 : 0;
    #pragma unroll
    for (int tile = 0; tile < 4; ++tile) {
        int col = cbl*64 + tile*16 + (lane & 15);
        float bv = bias[col];
        #pragma unroll
        for (int r = 0; r < 4; ++r) {
            int mm = row0 + w*16 + (lane >> 4)*4 + r;
            if (mm < n && kids[3*(start + mm) + 2] == want)
                hh[(size_t)(start + mm)*256 + col] = (_Float16)tanhf(acc[tile][r] + bv);
        }
    }
}

// ---------------------------------------------------------------------------
// Grid barrier: release add, RELAXED spin (no per-poll invalidation),
// single acquire fence on exit.
// ---------------------------------------------------------------------------
__device__ __forceinline__ void gbar(unsigned* bar, unsigned target)
{
    __syncthreads();
    if (threadIdx.x == 0) {
        __hip_atomic_fetch_add(bar, 1u, __ATOMIC_RELEASE, __HIP_MEMORY_SCOPE_AGENT);
        while (__hip_atomic_load(bar, __ATOMIC_RELAXED, __HIP_MEMORY_SCOPE_AGENT) < target)
            __builtin_amdgcn_s_sleep(4);
    }
    __syncthreads();
    __builtin_amdgcn_fence(__ATOMIC_ACQUIRE, "agent");
}

// ---------------------------------------------------------------------------
// Tail: levels n<=256 persistent, 48 blocks.
// Blocks 0-31: k1 (16 col-slices x 2 row-halves). 32-47: k2 (8 x 2).
// Weight slices pinned in LDS once. Root written at the end by block 0.
// ---------------------------------------------------------------------------
__global__ __launch_bounds__(256) void tail_kernel(
    _Float16* __restrict__ hh, const float* __restrict__ param,
    const _Float16* __restrict__ wcatpk, const _Float16* __restrict__ wscatpk,
    const float* __restrict__ b1, const float* __restrict__ bs1,
    _Float16* __restrict__ U, _Float16* __restrict__ V,
    const int* __restrict__ kids,
    const _Float16* __restrict__ w2pk, const _Float16* __restrict__ ws2pk,
    const float* __restrict__ b2, const float* __restrict__ bs2,
    unsigned* __restrict__ bar, float* __restrict__ out)
{
    __shared__ __align__(16) _Float16 wlds[16*2048];   // 64 KB
    const int b = blockIdx.x;          // 0..47
    const int t = threadIdx.x;
    const bool isK1 = b < 32;
    int cb, rh;
    const _Float16* src;
    int nh;
    if (isK1) {
        cb = b & 15; rh = b >> 4;
        if (cb < 8) { src = wcatpk  + (size_t)cb*16*2048;     nh = 16*256; }
        else        { src = wscatpk + (size_t)(cb-8)*10*2048; nh = 10*256; }
    } else {
        int i = b - 32; cb = i & 7; rh = i >> 3;
        if (cb < 4) src = w2pk  + (size_t)cb*16*2048;
        else        src = ws2pk + (size_t)(cb-4)*16*2048;
        nh = 16*256;
    }
    for (int i = t; i < nh; i += 256)
        *(half8*)(wlds + (size_t)i*8) = *(const half8*)(src + (size_t)i*8);
    __syncthreads();

    const unsigned G = gridDim.x;      // 48
    unsigned tgt = 0;
    int start = LEAF + 8192 + 4096 + 2048 + 1024 + 512;   // 32256, first level n=256
    for (int n = 256; n >= 1; n >>= 1) {
        int rt = (n + 63) >> 6;
        if (isK1) {
            for (int r = rh; r < rt; r += 2)
                k1_tail(r, cb, start, n, hh, param, wlds, b1, bs1, U, V);
        }
        tgt += G; gbar(bar, tgt);
        if (!isK1) {
            for (int r = rh; r < rt; r += 2)
                k2_tail(r, cb, start, n, U, V, kids, wlds, b2, bs2, hh);
        }
        tgt += G; gbar(bar, tgt);
        start += n;
    }
    if (b == 0)
        out[t] = (float)hh[(size_t)(NNODE - 1)*256 + t];
}

extern "C" void kernel_launch(void* const* d_in, const int* in_sizes, int n_in,
                              void* d_out, int out_size, void* d_ws, size_t ws_size,
                              hipStream_t stream) {
    const int*   kids  = (const int*)  d_in[0];
    const float* shape = (const float*)d_in[1];
    const float* param = (const float*)d_in[2];
    const float* Wb    = (const float*)d_in[3];
    const float* bb    = (const float*)d_in[4];
    const float* Wl    = (const float*)d_in[5];
    const float* Wr    = (const float*)d_in[6];
    const float* b1    = (const float*)d_in[7];
    const float* W2    = (const float*)d_in[8];
    const float* b2    = (const float*)d_in[9];
    const float* Wsl   = (const float*)d_in[10];
    const float* Wsr   = (const float*)d_in[11];
    const float* bs1   = (const float*)d_in[12];
    const float* Ws2   = (const float*)d_in[13];
    const float* bs2   = (const float*)d_in[14];
    float* out = (float*)d_out;

    char* ws = (char*)d_ws;
    _Float16* hh      = (_Float16*)(ws + 0);          // 16.8MB
    _Float16* U       = (_Float16*)(ws + 16777216);   // 8.4MB
    _Float16* V       = (_Float16*)(ws + 25165824);   // 8.4MB
    _Float16* wcatpk  = (_Float16*)(ws + 33554432);   // 512KB
    _Float16* wscatpk = (_Float16*)(ws + 34078720);   // 320KB
    _Float16* w2pk    = (_Float16*)(ws + 34406400);   // 256KB
    _Float16* ws2pk   = (_Float16*)(ws + 34668544);   // 256KB
    _Float16* wbpk    = (_Float16*)(ws + 34930688);   // 64KB
    unsigned* bar     = (unsigned*)(ws + 34996224);

    hipMemsetAsync(bar, 0, 256, stream);

    pack_kernel<<<1024, 256, 0, stream>>>(Wl,  Wr,  256, 512, 16, wcatpk,  262144);
    pack_kernel<<< 640, 256, 0, stream>>>(Wsl, Wsr, 256, 512, 10, wscatpk, 163840);
    pack_kernel<<< 512, 256, 0, stream>>>(W2,  W2,  512, 256, 16, w2pk,    131072);
    pack_kernel<<< 512, 256, 0, stream>>>(Ws2, Ws2, 512, 256, 16, ws2pk,   131072);
    pack_kernel<<< 128, 256, 0, stream>>>(Wb,  Wb,  128, 256,  4, wbpk,     32768);

    leaf_mfma_kernel<<<LEAF/64, 256, 0, stream>>>(shape, wbpk, bb, hh);

    int start = LEAF;
    for (int n = 8192; n >= 512; n >>= 1) {
        if (n == 8192) {
            k1_kernel<2><<<dim3(n/128, 16), 256, 0, stream>>>(hh, param, wcatpk, wscatpk,
                                                              b1, bs1, U, V, start, n);
        } else {
            k1_kernel<1><<<dim3(n/64, 16), 256, 0, stream>>>(hh, param, wcatpk, wscatpk,
                                                             b1, bs1, U, V, start, n);
        }
        k2_kernel<1><<<dim3(n/64, 8), 256, 0, stream>>>(U, V, kids, w2pk, ws2pk,
                                                        b2, bs2, hh, start, n);
        start += n;
    }

    tail_kernel<<<48, 256, 0, stream>>>(hh, param, wcatpk, wscatpk, b1, bs1,
                                        U, V, kids, w2pk, ws2pk, b2, bs2, bar, out);
}